// Round 9
// baseline (2145.140 us; speedup 1.0000x reference)
//
#include <hip/hip_runtime.h>
#include <hip/hip_bf16.h>
#include <hip/hip_cooperative_groups.h>

namespace cg = cooperative_groups;

#define NN 50000
#define EE 800000
#define GG 512
#define HH 256
#define TT 32
#define LL 4
#define EPSF 1e-5f
#define MPAD 50048

typedef __attribute__((ext_vector_type(8))) short short8;
typedef __attribute__((ext_vector_type(4))) float float4v;

// ---------- bf16 helpers ----------
__device__ inline unsigned short f2b(float f) {  // RNE
    unsigned u = __float_as_uint(f);
    unsigned r = (u + 0x7FFFu + ((u >> 16) & 1u)) >> 16;
    return (unsigned short)r;
}
__device__ inline unsigned pack2(float lo, float hi) {  // v_cvt_pk_bf16_f32
    __hip_bfloat162 b2 = __float22bfloat162_rn(float2{lo, hi});
    return *reinterpret_cast<unsigned*>(&b2);
}
__device__ inline float4 bf4_to_f4(ushort4 u) {
    float4 f;
    f.x = __uint_as_float((unsigned)u.x << 16);
    f.y = __uint_as_float((unsigned)u.y << 16);
    f.z = __uint_as_float((unsigned)u.z << 16);
    f.w = __uint_as_float((unsigned)u.w << 16);
    return f;
}

// ---------------- the mega kernel: everything after memset ----------------
// 256 threads/block, 4 blocks/CU (LDS 36864 B, VGPR<=128), cooperative launch.
__global__ __launch_bounds__(256, 4) void k_mega(
    const int* __restrict__ x, const int* __restrict__ tags,
    const int* __restrict__ ei, const int* __restrict__ batch,
    const float* __restrict__ atom_e, const float* __restrict__ tag_e,
    const float* __restrict__ Wp, const float* __restrict__ bp,
    const float* __restrict__ gcn_W, const float* __restrict__ gcn_b,
    const float* __restrict__ bn_g, const float* __restrict__ bn_b,
    const float* __restrict__ W1, const float* __restrict__ b1,
    const float* __restrict__ W2, const float* __restrict__ b2,
    float* __restrict__ out,
    unsigned short* __restrict__ hb, unsigned short* __restrict__ hwb,
    unsigned short* __restrict__ Wt, unsigned short* __restrict__ aggb,
    float* __restrict__ dinv, int* __restrict__ rs, int* __restrict__ csr,
    int* __restrict__ bsum, float* __restrict__ aref, float* __restrict__ tref,
    int* __restrict__ gstart, float* __restrict__ pooled,
    int* __restrict__ cnt, int* __restrict__ cur, float* __restrict__ cstat) {

    cg::grid_group gg = cg::this_grid();
    __shared__ __align__(16) char smem[36864];

    const int* src = ei;
    const int* dst = ei + EE;
    const int T = blockIdx.x * 256 + threadIdx.x;
    const int NT = gridDim.x * 256;
    const float invN = 1.0f / (float)NN;

    // ---- phase 1: degree ----
    for (int e = T; e < EE; e += NT) atomicAdd(&cnt[dst[e]], 1);
    gg.sync();

    // ---- phase 2: per-chunk (256) inclusive scan ----
    const int nch = (NN + 255) / 256;  // 196
    {
        int* si = (int*)smem;
        for (int ch = blockIdx.x; ch < nch; ch += gridDim.x) {
            int i = ch * 256 + threadIdx.x;
            int v = (i < NN) ? cnt[i] : 0;
            si[threadIdx.x] = v;
            __syncthreads();
            for (int off = 1; off < 256; off <<= 1) {
                int t = (threadIdx.x >= off) ? si[threadIdx.x - off] : 0;
                __syncthreads();
                si[threadIdx.x] += t;
                __syncthreads();
            }
            if (i < NN) rs[i] = si[threadIdx.x];
            if (threadIdx.x == 255) bsum[ch] = si[255];
            __syncthreads();
        }
    }
    gg.sync();

    // ---- phase 3: scan chunk partials (single block, nch<=256) ----
    if (blockIdx.x == 0) {
        int* si = (int*)smem;
        int v = (threadIdx.x < nch) ? bsum[threadIdx.x] : 0;
        si[threadIdx.x] = v;
        __syncthreads();
        for (int off = 1; off < 256; off <<= 1) {
            int t = (threadIdx.x >= off) ? si[threadIdx.x - off] : 0;
            __syncthreads();
            si[threadIdx.x] += t;
            __syncthreads();
        }
        if (threadIdx.x < nch) bsum[threadIdx.x] = si[threadIdx.x] - v;  // exclusive
    }
    gg.sync();

    // ---- phase 4: exclusive offsets + dinv ----
    for (int i = T; i < NN; i += NT) {
        int c = cnt[i];
        rs[i] = rs[i] + bsum[i >> 8] - c;
        dinv[i] = rsqrtf((float)c + 1.0f);
    }
    gg.sync();

    // ---- phase 5: scatter + gbound + projw (independent) ----
    for (int e = T; e < EE; e += NT) {
        int d = dst[e];
        int p = rs[d] + atomicAdd(&cur[d], 1);
        csr[p] = src[e];
    }
    for (int n = T; n < NN; n += NT) {
        int b = batch[n];
        int prev = (n == 0) ? -1 : batch[n - 1];
        for (int g = prev + 1; g <= b; ++g) gstart[g] = n;
        if (n == NN - 1)
            for (int g = b + 1; g <= GG; ++g) gstart[g] = NN;
    }
    for (int it = T; it < LL * 256 * 64; it += NT) {  // Wt[l][n][k] bf16
        int l = it >> 14;
        int rem = it & 16383;
        int n = rem >> 6;
        int kq = (rem & 63) * 4;
        const float* Wl = gcn_W + (size_t)l * HH * HH;
        ushort4 o;
        o.x = f2b(Wl[(size_t)(kq + 0) * HH + n]);
        o.y = f2b(Wl[(size_t)(kq + 1) * HH + n]);
        o.z = f2b(Wl[(size_t)(kq + 2) * HH + n]);
        o.w = f2b(Wl[(size_t)(kq + 3) * HH + n]);
        *(ushort4*)(Wt + (size_t)l * HH * HH + (size_t)n * HH + kq) = o;
    }
    for (int it = T; it < 103 * 256; it += NT) {  // aref/tref
        int r = it >> 8;
        int j = it & 255;
        if (r < 100) {
            float acc = bp[j];
            for (int k = 0; k < HH; ++k) acc += atom_e[r * HH + k] * Wp[(size_t)k * HH + j];
            aref[r * HH + j] = acc;
        } else {
            int tr = r - 100;
            float acc = 0.f;
            for (int k = 0; k < TT; ++k) acc += tag_e[tr * TT + k] * Wp[(size_t)(HH + k) * HH + j];
            tref[tr * HH + j] = acc;
        }
    }
    gg.sync();

    // ---- phase 6: h0 -> hb (bf16) ----
    for (int i = T; i < NN * 64; i += NT) {
        int n = i >> 6, lane = i & 63;
        float4 a = ((const float4*)(aref + (size_t)x[n] * HH))[lane];
        float4 t4 = ((const float4*)(tref + (size_t)tags[n] * HH))[lane];
        unsigned lo = pack2(a.x + t4.x, a.y + t4.y);
        unsigned hi = pack2(a.z + t4.z, a.w + t4.w);
        ((uint2*)hb)[i] = make_uint2(lo, hi);
    }
    gg.sync();

    // ---- layers ----
    for (int l = 0; l < LL; ++l) {
        if (l > 0) {
            // epi phase: hb += relu(bn(aggb)) in place, BN from cstat[l-1]
            float* sc = (float*)smem;
            float* sh = sc + 256;
            {
                int t = threadIdx.x;
                const float* cs = cstat + (size_t)(l - 1) * 512;
                float mu = cs[t] * invN;
                float var = cs[256 + t] * invN - mu * mu;
                float s = bn_g[(size_t)(l - 1) * HH + t] * rsqrtf(var + EPSF);
                sc[t] = s;
                sh[t] = bn_b[(size_t)(l - 1) * HH + t] - mu * s;
            }
            __syncthreads();
            for (int i = T; i < NN * 64; i += NT) {
                int q = (i & 63) * 4;
                float4 a = bf4_to_f4(((const ushort4*)aggb)[i]);
                float4 hv = bf4_to_f4(((const ushort4*)hb)[i]);
                hv.x += fmaxf(a.x * sc[q + 0] + sh[q + 0], 0.f);
                hv.y += fmaxf(a.y * sc[q + 1] + sh[q + 1], 0.f);
                hv.z += fmaxf(a.z * sc[q + 2] + sh[q + 2], 0.f);
                hv.w += fmaxf(a.w * sc[q + 3] + sh[q + 3], 0.f);
                unsigned lo = pack2(hv.x, hv.y);
                unsigned hi = pack2(hv.z, hv.w);
                ((uint2*)hb)[i] = make_uint2(lo, hi);
            }
            gg.sync();
        }

        // gemm phase: hwb = bf16((hb @ Wt_l^T) * dinv[row]); 128x128 tiles
        {
            unsigned short (*As)[72] = (unsigned short(*)[72])smem;
            unsigned short (*Bs)[72] = (unsigned short(*)[72])(smem + 18432);
            const unsigned short* Wl = Wt + (size_t)l * HH * HH;
            int t = threadIdx.x;
            int lane = t & 63, w = t >> 6;
            int wr = w >> 1, wc = w & 1;
            int l15 = lane & 15, l4 = lane >> 4;
            int ntile = (MPAD / 128) * 2;
            for (int job = blockIdx.x; job < ntile; job += gridDim.x) {
                int row0 = (job >> 1) * 128, col0 = (job & 1) * 128;
                float4v acc[4][4];
#pragma unroll
                for (int i = 0; i < 4; ++i)
#pragma unroll
                    for (int j = 0; j < 4; ++j) acc[i][j] = (float4v)0.f;
                for (int k0 = 0; k0 < 256; k0 += 64) {
                    __syncthreads();
#pragma unroll
                    for (int u = 0; u < 4; ++u) {
                        int idx = u * 256 + t;
                        int r = idx >> 3;
                        int c = (idx & 7) * 8;
                        int grow = row0 + r;
                        uint4 av = make_uint4(0u, 0u, 0u, 0u);
                        if (grow < NN) av = *(const uint4*)(hb + (size_t)grow * 256 + k0 + c);
                        *(uint4*)&As[r][c] = av;
                        *(uint4*)&Bs[r][c] = *(const uint4*)(Wl + (size_t)(col0 + r) * 256 + k0 + c);
                    }
                    __syncthreads();
#pragma unroll
                    for (int kk = 0; kk < 64; kk += 32) {
                        short8 a[4], b[4];
#pragma unroll
                        for (int i = 0; i < 4; ++i)
                            a[i] = *(const short8*)&As[wr * 64 + i * 16 + l15][kk + l4 * 8];
#pragma unroll
                        for (int i = 0; i < 4; ++i)
                            b[i] = *(const short8*)&Bs[wc * 64 + i * 16 + l15][kk + l4 * 8];
#pragma unroll
                        for (int mi = 0; mi < 4; ++mi)
#pragma unroll
                            for (int ni = 0; ni < 4; ++ni)
                                acc[mi][ni] = __builtin_amdgcn_mfma_f32_16x16x32_bf16(
                                    a[mi], b[ni], acc[mi][ni], 0, 0, 0);
                    }
                }
                // epilogue: C/D layout col=lane&15, row=(lane>>4)*4+reg
#pragma unroll
                for (int mi = 0; mi < 4; ++mi) {
                    int mb = row0 + wr * 64 + mi * 16 + l4 * 4;
                    float dv[4];
#pragma unroll
                    for (int r = 0; r < 4; ++r) dv[r] = (mb + r < NN) ? dinv[mb + r] : 0.f;
#pragma unroll
                    for (int ni = 0; ni < 4; ++ni) {
                        int n = col0 + wc * 64 + ni * 16 + l15;
#pragma unroll
                        for (int r = 0; r < 4; ++r) {
                            if (mb + r < NN)
                                hwb[(size_t)(mb + r) * 256 + n] = f2b(acc[mi][ni][r] * dv[r]);
                        }
                    }
                }
                __syncthreads();
            }
        }
        gg.sync();

        // agg phase: one wave per node, bf16 row gathers
        {
            const float* bias = gcn_b + (size_t)l * HH;
            int wave = threadIdx.x >> 6;
            int lane = threadIdx.x & 63;
            for (int base = blockIdx.x * 4; base < NN; base += gridDim.x * 4) {
                int n = base + wave;
                if (n >= NN) continue;
                float dn = dinv[n];
                int e = rs[n];
                int end = e + cnt[n];
                float4 acc = bf4_to_f4(((const ushort4*)(hwb + (size_t)n * HH))[lane]);
                for (; e + 8 <= end; e += 8) {
                    int s0 = csr[e],     s1 = csr[e + 1], s2 = csr[e + 2], s3 = csr[e + 3];
                    int s4 = csr[e + 4], s5 = csr[e + 5], s6 = csr[e + 6], s7 = csr[e + 7];
                    float4 m0 = bf4_to_f4(((const ushort4*)(hwb + (size_t)s0 * HH))[lane]);
                    float4 m1 = bf4_to_f4(((const ushort4*)(hwb + (size_t)s1 * HH))[lane]);
                    float4 m2 = bf4_to_f4(((const ushort4*)(hwb + (size_t)s2 * HH))[lane]);
                    float4 m3 = bf4_to_f4(((const ushort4*)(hwb + (size_t)s3 * HH))[lane]);
                    float4 m4 = bf4_to_f4(((const ushort4*)(hwb + (size_t)s4 * HH))[lane]);
                    float4 m5 = bf4_to_f4(((const ushort4*)(hwb + (size_t)s5 * HH))[lane]);
                    float4 m6 = bf4_to_f4(((const ushort4*)(hwb + (size_t)s6 * HH))[lane]);
                    float4 m7 = bf4_to_f4(((const ushort4*)(hwb + (size_t)s7 * HH))[lane]);
                    acc.x += ((m0.x + m1.x) + (m2.x + m3.x)) + ((m4.x + m5.x) + (m6.x + m7.x));
                    acc.y += ((m0.y + m1.y) + (m2.y + m3.y)) + ((m4.y + m5.y) + (m6.y + m7.y));
                    acc.z += ((m0.z + m1.z) + (m2.z + m3.z)) + ((m4.z + m5.z) + (m6.z + m7.z));
                    acc.w += ((m0.w + m1.w) + (m2.w + m3.w)) + ((m4.w + m5.w) + (m6.w + m7.w));
                }
                for (; e + 4 <= end; e += 4) {
                    int s0 = csr[e], s1 = csr[e + 1], s2 = csr[e + 2], s3 = csr[e + 3];
                    float4 m0 = bf4_to_f4(((const ushort4*)(hwb + (size_t)s0 * HH))[lane]);
                    float4 m1 = bf4_to_f4(((const ushort4*)(hwb + (size_t)s1 * HH))[lane]);
                    float4 m2 = bf4_to_f4(((const ushort4*)(hwb + (size_t)s2 * HH))[lane]);
                    float4 m3 = bf4_to_f4(((const ushort4*)(hwb + (size_t)s3 * HH))[lane]);
                    acc.x += (m0.x + m1.x) + (m2.x + m3.x);
                    acc.y += (m0.y + m1.y) + (m2.y + m3.y);
                    acc.z += (m0.z + m1.z) + (m2.z + m3.z);
                    acc.w += (m0.w + m1.w) + (m2.w + m3.w);
                }
                for (; e < end; ++e) {
                    int s = csr[e];
                    float4 m = bf4_to_f4(((const ushort4*)(hwb + (size_t)s * HH))[lane]);
                    acc.x += m.x; acc.y += m.y; acc.z += m.z; acc.w += m.w;
                }
                float4 b = ((const float4*)bias)[lane];
                ushort4 u;
                u.x = f2b(acc.x * dn + b.x); u.y = f2b(acc.y * dn + b.y);
                u.z = f2b(acc.z * dn + b.z); u.w = f2b(acc.w * dn + b.w);
                ((ushort4*)(aggb + (size_t)n * HH))[lane] = u;
            }
        }
        gg.sync();

        // bnstats phase
        {
            float* colsum = cstat + (size_t)l * 512;
            float* colsq = colsum + 256;
            float4 (*ssum)[64] = (float4(*)[64])smem;
            float4 (*ssq)[64] = (float4(*)[64])(smem + 4096);
            int lane = threadIdx.x & 63;
            int wv = threadIdx.x >> 6;
            int rows_per = (NN + gridDim.x - 1) / gridDim.x;
            int r0 = blockIdx.x * rows_per;
            int r1 = r0 + rows_per; if (r1 > NN) r1 = NN;
            float4 s = make_float4(0.f, 0.f, 0.f, 0.f);
            float4 s2 = make_float4(0.f, 0.f, 0.f, 0.f);
            for (int r = r0 + wv; r < r1; r += 4) {
                float4 v = bf4_to_f4(((const ushort4*)aggb)[(size_t)r * 64 + lane]);
                s.x += v.x; s.y += v.y; s.z += v.z; s.w += v.w;
                s2.x += v.x * v.x; s2.y += v.y * v.y; s2.z += v.z * v.z; s2.w += v.w * v.w;
            }
            ssum[wv][lane] = s;
            ssq[wv][lane] = s2;
            __syncthreads();
            int j = lane * 4;
            if (wv == 0) {
                float4 a = ssum[0][lane], b = ssum[1][lane], c = ssum[2][lane], d = ssum[3][lane];
                atomicAdd(&colsum[j + 0], a.x + b.x + c.x + d.x);
                atomicAdd(&colsum[j + 1], a.y + b.y + c.y + d.y);
                atomicAdd(&colsum[j + 2], a.z + b.z + c.z + d.z);
                atomicAdd(&colsum[j + 3], a.w + b.w + c.w + d.w);
            } else if (wv == 1) {
                float4 a = ssq[0][lane], b = ssq[1][lane], c = ssq[2][lane], d = ssq[3][lane];
                atomicAdd(&colsq[j + 0], a.x + b.x + c.x + d.x);
                atomicAdd(&colsq[j + 1], a.y + b.y + c.y + d.y);
                atomicAdd(&colsq[j + 2], a.z + b.z + c.z + d.z);
                atomicAdd(&colsq[j + 3], a.w + b.w + c.w + d.w);
            }
            __syncthreads();
        }
        gg.sync();
    }

    // ---- pool phase (fused layer-3 BN/ReLU/residual) ----
    {
        const float* colsum = cstat + 3 * 512;
        const float* colsq = colsum + 256;
        const float* bng = bn_g + 3 * HH;
        const float* bnb = bn_b + 3 * HH;
        float4 (*sm)[64] = (float4(*)[64])smem;
        int t = threadIdx.x;
        int lane = t & 63, wv = t >> 6;
        int col = lane * 4;
        float4 cs = *(const float4*)(colsum + col);
        float4 cq = *(const float4*)(colsq + col);
        float4 g4 = *(const float4*)(bng + col);
        float4 b4 = *(const float4*)(bnb + col);
        float4 scl, shf;
        float mu, var;
        mu = cs.x * invN; var = cq.x * invN - mu * mu; scl.x = g4.x * rsqrtf(var + EPSF); shf.x = b4.x - mu * scl.x;
        mu = cs.y * invN; var = cq.y * invN - mu * mu; scl.y = g4.y * rsqrtf(var + EPSF); shf.y = b4.y - mu * scl.y;
        mu = cs.z * invN; var = cq.z * invN - mu * mu; scl.z = g4.z * rsqrtf(var + EPSF); shf.z = b4.z - mu * scl.z;
        mu = cs.w * invN; var = cq.w * invN - mu * mu; scl.w = g4.w * rsqrtf(var + EPSF); shf.w = b4.w - mu * scl.w;
        for (int g = blockIdx.x; g < GG; g += gridDim.x) {
            int s = gstart[g], e = gstart[g + 1];
            float4 acc = make_float4(0.f, 0.f, 0.f, 0.f);
            for (int n = s + wv; n < e; n += 4) {
                float4 hv = bf4_to_f4(((const ushort4*)hb)[(size_t)n * 64 + lane]);
                float4 av = bf4_to_f4(((const ushort4*)aggb)[(size_t)n * 64 + lane]);
                acc.x += hv.x + fmaxf(av.x * scl.x + shf.x, 0.f);
                acc.y += hv.y + fmaxf(av.y * scl.y + shf.y, 0.f);
                acc.z += hv.z + fmaxf(av.z * scl.z + shf.z, 0.f);
                acc.w += hv.w + fmaxf(av.w * scl.w + shf.w, 0.f);
            }
            sm[wv][lane] = acc;
            __syncthreads();
            if (wv == 0) {
                float4 a = sm[0][lane], b = sm[1][lane], c = sm[2][lane], d = sm[3][lane];
                float inv = 1.0f / fmaxf((float)(e - s), 1.0f);
                float4 r;
                r.x = (a.x + b.x + c.x + d.x) * inv;
                r.y = (a.y + b.y + c.y + d.y) * inv;
                r.z = (a.z + b.z + c.z + d.z) * inv;
                r.w = (a.w + b.w + c.w + d.w) * inv;
                ((float4*)pooled)[(size_t)g * 64 + lane] = r;
            }
            __syncthreads();
        }
    }
    gg.sync();

    // ---- head phase ----
    {
        float* prow = (float*)smem;
        float* hred = prow + 256;
        int t = threadIdx.x;
        for (int g = blockIdx.x; g < GG; g += gridDim.x) {
            if (t < 128) {
                prow[t] = pooled[(size_t)g * HH + t];
                prow[t + 128] = pooled[(size_t)g * HH + t + 128];
            }
            __syncthreads();
            if (t < 128) {
                float acc = b1[t];
                for (int k = 0; k < HH; ++k) acc += prow[k] * W1[(size_t)k * 128 + t];
                hred[t] = fmaxf(acc, 0.f) * W2[t];
            }
            __syncthreads();
            for (int off = 64; off > 0; off >>= 1) {
                if (t < off) hred[t] += hred[t + off];
                __syncthreads();
            }
            if (t == 0) out[g] = hred[0] + b2[0];
            __syncthreads();
        }
    }
}

extern "C" void kernel_launch(void* const* d_in, const int* in_sizes, int n_in,
                              void* d_out, int out_size, void* d_ws, size_t ws_size,
                              hipStream_t stream) {
    const int* x        = (const int*)d_in[0];
    const int* tags     = (const int*)d_in[1];
    const int* ei       = (const int*)d_in[2];
    const int* batch    = (const int*)d_in[3];
    const float* atom_e = (const float*)d_in[4];
    const float* tag_e  = (const float*)d_in[5];
    const float* Wp     = (const float*)d_in[6];
    const float* bp     = (const float*)d_in[7];
    const float* gcn_W  = (const float*)d_in[8];
    const float* gcn_b  = (const float*)d_in[9];
    const float* bn_g   = (const float*)d_in[10];
    const float* bn_b   = (const float*)d_in[11];
    const float* W1     = (const float*)d_in[12];
    const float* b1     = (const float*)d_in[13];
    const float* W2     = (const float*)d_in[14];
    const float* b2     = (const float*)d_in[15];
    float* out = (float*)d_out;

    char* p = (char*)d_ws;
    auto alloc = [&](size_t bytes) {
        void* r = (void*)p;
        p += (bytes + 255) & ~(size_t)255;
        return r;
    };
    unsigned short* hb  = (unsigned short*)alloc((size_t)MPAD * HH * 2);
    unsigned short* hwb = (unsigned short*)alloc((size_t)MPAD * HH * 2);
    unsigned short* Wt  = (unsigned short*)alloc((size_t)LL * HH * HH * 2);
    unsigned short* aggb= (unsigned short*)alloc((size_t)NN * HH * 2);
    float* dinv = (float*)alloc((size_t)NN * 4);
    int* rs     = (int*)alloc((size_t)NN * 4);
    int* csr    = (int*)alloc((size_t)EE * 4);
    int* bsum   = (int*)alloc(256 * 4);
    float* aref = (float*)alloc(100 * (size_t)HH * 4);
    float* tref = (float*)alloc(3 * (size_t)HH * 4);
    int* gstart = (int*)alloc((size_t)(GG + 1) * 4);
    float* pooled = (float*)alloc((size_t)GG * HH * 4);
    // zero region: cnt | cur | cstat (contiguous, one memset)
    int* cnt    = (int*)alloc((size_t)NN * 4);
    int* cur    = (int*)alloc((size_t)NN * 4);
    float* cstat= (float*)alloc((size_t)LL * 512 * 4);
    size_t zspan = (size_t)((char*)cstat + (size_t)LL * 512 * 4 - (char*)cnt);

    hipMemsetAsync(cnt, 0, zspan, stream);

    int occ = 0;
    hipOccupancyMaxActiveBlocksPerMultiprocessor(&occ, (const void*)k_mega, 256, 0);
    if (occ < 1) occ = 1;
    if (occ > 4) occ = 4;
    int grid = occ * 256;  // 256 CUs on MI355X

    void* params[] = {
        (void*)&x, (void*)&tags, (void*)&ei, (void*)&batch,
        (void*)&atom_e, (void*)&tag_e, (void*)&Wp, (void*)&bp,
        (void*)&gcn_W, (void*)&gcn_b, (void*)&bn_g, (void*)&bn_b,
        (void*)&W1, (void*)&b1, (void*)&W2, (void*)&b2,
        (void*)&out,
        (void*)&hb, (void*)&hwb, (void*)&Wt, (void*)&aggb,
        (void*)&dinv, (void*)&rs, (void*)&csr, (void*)&bsum,
        (void*)&aref, (void*)&tref, (void*)&gstart, (void*)&pooled,
        (void*)&cnt, (void*)&cur, (void*)&cstat
    };
    hipLaunchCooperativeKernel((const void*)k_mega, dim3(grid), dim3(256),
                               params, 0, stream);
}

// Round 10
// 809.161 us; speedup vs baseline: 2.6511x; 2.6511x over previous
//
#include <hip/hip_runtime.h>
#include <hip/hip_bf16.h>

#define NN 50000
#define EE 800000
#define GG 512
#define HH 256
#define TT 32
#define LL 4
#define EPSF 1e-5f

typedef __attribute__((ext_vector_type(8))) short short8;
typedef __attribute__((ext_vector_type(4))) float float4v;

// ---------- bf16 helpers ----------
__device__ inline unsigned short f2b(float f) {  // RNE
    unsigned u = __float_as_uint(f);
    unsigned r = (u + 0x7FFFu + ((u >> 16) & 1u)) >> 16;
    return (unsigned short)r;
}
__device__ inline unsigned pack2(float lo, float hi) {  // v_cvt_pk_bf16_f32
    __hip_bfloat162 b2 = __float22bfloat162_rn(float2{lo, hi});
    return *reinterpret_cast<unsigned*>(&b2);
}
__device__ inline float4 bf4_to_f4(ushort4 u) {
    float4 f;
    f.x = __uint_as_float((unsigned)u.x << 16);
    f.y = __uint_as_float((unsigned)u.y << 16);
    f.z = __uint_as_float((unsigned)u.z << 16);
    f.w = __uint_as_float((unsigned)u.w << 16);
    return f;
}

// ---------------- degree ----------------
__global__ void k_degree(const int* __restrict__ dst, int* __restrict__ cnt, int E) {
    int e = blockIdx.x * 256 + threadIdx.x;
    if (e < E) atomicAdd(&cnt[dst[e]], 1);
}

// ---------------- scan (3-phase) ----------------
__global__ void k_scan1(const int* __restrict__ cnt, int* __restrict__ incl,
                        int* __restrict__ bsum, int N) {
    __shared__ int s[1024];
    int i = blockIdx.x * 1024 + threadIdx.x;
    int v = (i < N) ? cnt[i] : 0;
    s[threadIdx.x] = v;
    __syncthreads();
    for (int off = 1; off < 1024; off <<= 1) {
        int t = (threadIdx.x >= off) ? s[threadIdx.x - off] : 0;
        __syncthreads();
        s[threadIdx.x] += t;
        __syncthreads();
    }
    if (i < N) incl[i] = s[threadIdx.x];
    if (threadIdx.x == 1023) bsum[blockIdx.x] = s[1023];
}

__global__ void k_scan2(int* __restrict__ bsum, int nb) {
    __shared__ int s[64];
    int v = (threadIdx.x < nb) ? bsum[threadIdx.x] : 0;
    s[threadIdx.x] = v;
    __syncthreads();
    for (int off = 1; off < 64; off <<= 1) {
        int t = (threadIdx.x >= off) ? s[threadIdx.x - off] : 0;
        __syncthreads();
        s[threadIdx.x] += t;
        __syncthreads();
    }
    if (threadIdx.x < nb) bsum[threadIdx.x] = s[threadIdx.x] - v;  // exclusive
}

// scan3 + dinv fused
__global__ void k_scan3(int* __restrict__ rs, const int* __restrict__ cnt,
                        const int* __restrict__ boff, float* __restrict__ dinv, int N) {
    int i = blockIdx.x * 256 + threadIdx.x;
    if (i < N) {
        int c = cnt[i];
        rs[i] = rs[i] + boff[i >> 10] - c;  // exclusive prefix
        dinv[i] = rsqrtf((float)c + 1.0f);
    }
}

// ---------------- merged prep: scatter | gbound | projw (independent jobs) ----------------
// grid = 3125 (scatter) + 196 (gbound) + 359 (projw: 256 wprep + 103 tables)
__global__ void k_prep(const int* __restrict__ src, const int* __restrict__ dst,
                       const int* __restrict__ rs, int* __restrict__ cur,
                       int* __restrict__ csr,
                       const int* __restrict__ batch, int* __restrict__ gstart,
                       const float* __restrict__ atom_emb, const float* __restrict__ tag_emb,
                       const float* __restrict__ Wp, const float* __restrict__ bp,
                       const float* __restrict__ W,
                       float* __restrict__ aref, float* __restrict__ tref,
                       unsigned short* __restrict__ Wt) {
    int blk = blockIdx.x;
    if (blk < 3125) {  // scatter
        int e = blk * 256 + threadIdx.x;
        if (e >= EE) return;
        int d = dst[e];
        int p = rs[d] + atomicAdd(&cur[d], 1);
        csr[p] = src[e];
    } else if (blk < 3125 + 196) {  // gbound
        int n = (blk - 3125) * 256 + threadIdx.x;
        if (n >= NN) return;
        int b = batch[n];
        int prev = (n == 0) ? -1 : batch[n - 1];
        for (int g = prev + 1; g <= b; ++g) gstart[g] = n;
        if (n == NN - 1)
            for (int g = b + 1; g <= GG; ++g) gstart[g] = NN;
    } else {
        int pb = blk - 3321;  // 0..358
        if (pb < 256) {  // wprep: Wt[l][n][k] bf16
            int l = pb >> 6;
            int bx = pb & 63;
            int n = bx * 4 + (threadIdx.x >> 6);
            int kq = (threadIdx.x & 63) * 4;
            const float* Wl = W + (size_t)l * HH * HH;
            ushort4 o;
            o.x = f2b(Wl[(size_t)(kq + 0) * HH + n]);
            o.y = f2b(Wl[(size_t)(kq + 1) * HH + n]);
            o.z = f2b(Wl[(size_t)(kq + 2) * HH + n]);
            o.w = f2b(Wl[(size_t)(kq + 3) * HH + n]);
            *(ushort4*)(Wt + (size_t)l * HH * HH + (size_t)n * HH + kq) = o;
        } else {
            int r = pb - 256;  // 0..102
            int j = threadIdx.x;
            if (r < 100) {
                float acc = bp[j];
                for (int k = 0; k < HH; ++k) acc += atom_emb[r * HH + k] * Wp[(size_t)k * HH + j];
                aref[r * HH + j] = acc;
            } else {
                int tr = r - 100;
                float acc = 0.f;
                for (int k = 0; k < TT; ++k) acc += tag_emb[tr * TT + k] * Wp[(size_t)(HH + k) * HH + j];
                tref[tr * HH + j] = acc;
            }
        }
    }
}

// ---------------- fused MFMA GEMM, 128x256 tile, single A pass ----------------
// hwb[M,256] = bf16( (A @ Wt^T) * dinv[row] )
// mode 0 (layer 0): A[row] = aref[x[row]] + tref[tags[row]]        (h0 fused)
// mode 1 (layers 1+): A[row] = hb_read[row] + relu(bn(aggb[row]))  (epi fused)
// Each block covers all 256 output cols, so A is computed once and written to hb_out.
__global__ __launch_bounds__(512, 2) void k_gemm(
    const unsigned short* __restrict__ hb_read,
    const unsigned short* __restrict__ Wt,
    const float* __restrict__ dinv,
    unsigned short* __restrict__ hwb,
    int mode,
    const int* __restrict__ x, const int* __restrict__ tags,
    const float* __restrict__ aref, const float* __restrict__ tref,
    const unsigned short* __restrict__ aggb,
    const float* __restrict__ colsum, const float* __restrict__ colsq,
    const float* __restrict__ bng, const float* __restrict__ bnb,
    unsigned short* __restrict__ hb_out,
    int M, float invN) {
    __shared__ unsigned short As[128][72];
    __shared__ unsigned short Bs[256][72];
    __shared__ float sc[256], sh[256];
    int t = threadIdx.x;              // 0..511
    int lane = t & 63, w = t >> 6;    // 8 waves
    int wr = w & 1, wc = w >> 1;      // wave covers rows [wr*64,+64), cols [wc*64,+64)
    int l15 = lane & 15, l4 = lane >> 4;
    int row0 = blockIdx.x * 128;

    if (mode == 1 && t < 256) {  // per-column BN scale/shift
        float mu = colsum[t] * invN;
        float var = colsq[t] * invN - mu * mu;
        float s = bng[t] * rsqrtf(var + EPSF);
        sc[t] = s;
        sh[t] = bnb[t] - mu * s;
    }
    __syncthreads();

    float4v acc[4][4];
#pragma unroll
    for (int i = 0; i < 4; ++i)
#pragma unroll
        for (int j = 0; j < 4; ++j) acc[i][j] = (float4v)0.f;

    for (int k0 = 0; k0 < 256; k0 += 64) {
        if (k0) __syncthreads();
        // B tile: 256 n-rows x 64 k
#pragma unroll
        for (int u = 0; u < 4; ++u) {
            int idx = u * 512 + t;          // 0..2047
            int rb = idx >> 3;              // 0..255
            int c = (idx & 7) * 8;
            *(uint4*)&Bs[rb][c] = *(const uint4*)(Wt + (size_t)rb * 256 + k0 + c);
        }
        // A tile: 128 rows x 64 k (computed once per row-block)
#pragma unroll
        for (int u = 0; u < 2; ++u) {
            int idx = u * 512 + t;          // 0..1023
            int r = idx >> 3;               // 0..127
            int c = (idx & 7) * 8;
            int grow = row0 + r;
            int gcol = k0 + c;
            uint4 ov;
            if (grow < M) {
                unsigned o[4];
                if (mode == 0) {
                    const float* ar = aref + (size_t)x[grow] * 256 + gcol;
                    const float* tr = tref + (size_t)tags[grow] * 256 + gcol;
                    float4 a0 = *(const float4*)ar, a1 = *(const float4*)(ar + 4);
                    float4 t0 = *(const float4*)tr, t1 = *(const float4*)(tr + 4);
                    o[0] = pack2(a0.x + t0.x, a0.y + t0.y);
                    o[1] = pack2(a0.z + t0.z, a0.w + t0.w);
                    o[2] = pack2(a1.x + t1.x, a1.y + t1.y);
                    o[3] = pack2(a1.z + t1.z, a1.w + t1.w);
                } else {
                    uint4 hv = *(const uint4*)(hb_read + (size_t)grow * 256 + gcol);
                    uint4 av = *(const uint4*)(aggb + (size_t)grow * 256 + gcol);
                    const unsigned* hvp = (const unsigned*)&hv;
                    const unsigned* avp = (const unsigned*)&av;
#pragma unroll
                    for (int j = 0; j < 4; ++j) {
                        unsigned hj = hvp[j], aj = avp[j];
                        float h0 = __uint_as_float(hj << 16);
                        float h1 = __uint_as_float(hj & 0xFFFF0000u);
                        float a0 = __uint_as_float(aj << 16);
                        float a1 = __uint_as_float(aj & 0xFFFF0000u);
                        int cc = gcol + j * 2;
                        float v0 = fmaxf(a0 * sc[cc] + sh[cc], 0.f);
                        float v1 = fmaxf(a1 * sc[cc + 1] + sh[cc + 1], 0.f);
                        o[j] = pack2(h0 + v0, h1 + v1);
                    }
                }
                ov = make_uint4(o[0], o[1], o[2], o[3]);
                *(uint4*)(hb_out + (size_t)grow * 256 + gcol) = ov;
            } else {
                ov = make_uint4(0u, 0u, 0u, 0u);
            }
            *(uint4*)&As[r][c] = ov;
        }
        __syncthreads();
#pragma unroll
        for (int kk = 0; kk < 64; kk += 32) {
            short8 a[4], b[4];
#pragma unroll
            for (int i = 0; i < 4; ++i)
                a[i] = *(const short8*)&As[wr * 64 + i * 16 + l15][kk + l4 * 8];
#pragma unroll
            for (int i = 0; i < 4; ++i)
                b[i] = *(const short8*)&Bs[wc * 64 + i * 16 + l15][kk + l4 * 8];
#pragma unroll
            for (int mi = 0; mi < 4; ++mi)
#pragma unroll
                for (int ni = 0; ni < 4; ++ni)
                    acc[mi][ni] = __builtin_amdgcn_mfma_f32_16x16x32_bf16(
                        a[mi], b[ni], acc[mi][ni], 0, 0, 0);
        }
    }
    // epilogue: C/D layout col=lane&15, row=(lane>>4)*4+reg
#pragma unroll
    for (int mi = 0; mi < 4; ++mi) {
        int mb = row0 + wr * 64 + mi * 16 + l4 * 4;
        float dv[4];
#pragma unroll
        for (int r = 0; r < 4; ++r) dv[r] = (mb + r < M) ? dinv[mb + r] : 0.f;
#pragma unroll
        for (int ni = 0; ni < 4; ++ni) {
            int n = wc * 64 + ni * 16 + l15;
#pragma unroll
            for (int r = 0; r < 4; ++r) {
                if (mb + r < M)
                    hwb[(size_t)(mb + r) * 256 + n] = f2b(acc[mi][ni][r] * dv[r]);
            }
        }
    }
}

// ---------------- CSR aggregation (bf16 row gathers, 8x unrolled): one wave/node ----------------
__global__ void k_agg(const unsigned short* __restrict__ hwb, unsigned short* __restrict__ aggb,
                      const int* __restrict__ csr, const int* __restrict__ rs,
                      const int* __restrict__ cnt, const float* __restrict__ dinv,
                      const float* __restrict__ bias, int N) {
    int wave = threadIdx.x >> 6;
    int lane = threadIdx.x & 63;
    int n = blockIdx.x * 4 + wave;
    if (n >= N) return;
    float dn = dinv[n];
    int e = rs[n];
    int end = e + cnt[n];
    // self term (hwb already carries dinv[src])
    float4 acc = bf4_to_f4(((const ushort4*)(hwb + (size_t)n * HH))[lane]);
    for (; e + 8 <= end; e += 8) {
        int s0 = csr[e],     s1 = csr[e + 1], s2 = csr[e + 2], s3 = csr[e + 3];
        int s4 = csr[e + 4], s5 = csr[e + 5], s6 = csr[e + 6], s7 = csr[e + 7];
        float4 m0 = bf4_to_f4(((const ushort4*)(hwb + (size_t)s0 * HH))[lane]);
        float4 m1 = bf4_to_f4(((const ushort4*)(hwb + (size_t)s1 * HH))[lane]);
        float4 m2 = bf4_to_f4(((const ushort4*)(hwb + (size_t)s2 * HH))[lane]);
        float4 m3 = bf4_to_f4(((const ushort4*)(hwb + (size_t)s3 * HH))[lane]);
        float4 m4 = bf4_to_f4(((const ushort4*)(hwb + (size_t)s4 * HH))[lane]);
        float4 m5 = bf4_to_f4(((const ushort4*)(hwb + (size_t)s5 * HH))[lane]);
        float4 m6 = bf4_to_f4(((const ushort4*)(hwb + (size_t)s6 * HH))[lane]);
        float4 m7 = bf4_to_f4(((const ushort4*)(hwb + (size_t)s7 * HH))[lane]);
        acc.x += ((m0.x + m1.x) + (m2.x + m3.x)) + ((m4.x + m5.x) + (m6.x + m7.x));
        acc.y += ((m0.y + m1.y) + (m2.y + m3.y)) + ((m4.y + m5.y) + (m6.y + m7.y));
        acc.z += ((m0.z + m1.z) + (m2.z + m3.z)) + ((m4.z + m5.z) + (m6.z + m7.z));
        acc.w += ((m0.w + m1.w) + (m2.w + m3.w)) + ((m4.w + m5.w) + (m6.w + m7.w));
    }
    for (; e + 4 <= end; e += 4) {
        int s0 = csr[e], s1 = csr[e + 1], s2 = csr[e + 2], s3 = csr[e + 3];
        float4 m0 = bf4_to_f4(((const ushort4*)(hwb + (size_t)s0 * HH))[lane]);
        float4 m1 = bf4_to_f4(((const ushort4*)(hwb + (size_t)s1 * HH))[lane]);
        float4 m2 = bf4_to_f4(((const ushort4*)(hwb + (size_t)s2 * HH))[lane]);
        float4 m3 = bf4_to_f4(((const ushort4*)(hwb + (size_t)s3 * HH))[lane]);
        acc.x += (m0.x + m1.x) + (m2.x + m3.x);
        acc.y += (m0.y + m1.y) + (m2.y + m3.y);
        acc.z += (m0.z + m1.z) + (m2.z + m3.z);
        acc.w += (m0.w + m1.w) + (m2.w + m3.w);
    }
    for (; e < end; ++e) {
        int s = csr[e];
        float4 m = bf4_to_f4(((const ushort4*)(hwb + (size_t)s * HH))[lane]);
        acc.x += m.x; acc.y += m.y; acc.z += m.z; acc.w += m.w;
    }
    float4 b = ((const float4*)bias)[lane];
    ushort4 u;
    u.x = f2b(acc.x * dn + b.x); u.y = f2b(acc.y * dn + b.y);
    u.z = f2b(acc.z * dn + b.z); u.w = f2b(acc.w * dn + b.w);
    ((ushort4*)(aggb + (size_t)n * HH))[lane] = u;
}

// ---------------- BN stats (col sum / sumsq) over bf16 agg ----------------
__global__ __launch_bounds__(256) void k_bnstats(const ushort4* __restrict__ aggb,
                                                 float* __restrict__ colsum,
                                                 float* __restrict__ colsq, int N) {
    __shared__ float4 ssum[4][64];
    __shared__ float4 ssq[4][64];
    int lane = threadIdx.x & 63;
    int wv = threadIdx.x >> 6;
    int rows_per = (N + gridDim.x - 1) / gridDim.x;
    int r0 = blockIdx.x * rows_per;
    int r1 = r0 + rows_per; if (r1 > N) r1 = N;
    float4 s = make_float4(0.f, 0.f, 0.f, 0.f);
    float4 s2 = make_float4(0.f, 0.f, 0.f, 0.f);
    for (int r = r0 + wv; r < r1; r += 4) {
        float4 v = bf4_to_f4(aggb[(size_t)r * 64 + lane]);
        s.x += v.x; s.y += v.y; s.z += v.z; s.w += v.w;
        s2.x += v.x * v.x; s2.y += v.y * v.y; s2.z += v.z * v.z; s2.w += v.w * v.w;
    }
    ssum[wv][lane] = s;
    ssq[wv][lane] = s2;
    __syncthreads();
    int j = lane * 4;
    if (wv == 0) {
        float4 a = ssum[0][lane], b = ssum[1][lane], c = ssum[2][lane], d = ssum[3][lane];
        atomicAdd(&colsum[j + 0], a.x + b.x + c.x + d.x);
        atomicAdd(&colsum[j + 1], a.y + b.y + c.y + d.y);
        atomicAdd(&colsum[j + 2], a.z + b.z + c.z + d.z);
        atomicAdd(&colsum[j + 3], a.w + b.w + c.w + d.w);
    } else if (wv == 1) {
        float4 a = ssq[0][lane], b = ssq[1][lane], c = ssq[2][lane], d = ssq[3][lane];
        atomicAdd(&colsq[j + 0], a.x + b.x + c.x + d.x);
        atomicAdd(&colsq[j + 1], a.y + b.y + c.y + d.y);
        atomicAdd(&colsq[j + 2], a.z + b.z + c.z + d.z);
        atomicAdd(&colsq[j + 3], a.w + b.w + c.w + d.w);
    }
}

// ---------------- pool (fused layer-3 epi) + MLP head, one block per graph ----------------
__global__ __launch_bounds__(256) void k_poolhead(
    const unsigned short* __restrict__ hb, const unsigned short* __restrict__ aggb,
    const int* __restrict__ gstart,
    const float* __restrict__ colsum, const float* __restrict__ colsq,
    const float* __restrict__ bng, const float* __restrict__ bnb,
    const float* __restrict__ W1, const float* __restrict__ b1,
    const float* __restrict__ W2, const float* __restrict__ b2,
    float* __restrict__ out, float invN) {
    __shared__ float4 sm[4][64];
    __shared__ float prow[256];
    __shared__ float hred[128];
    int g = blockIdx.x;
    int t = threadIdx.x;
    int lane = t & 63, wv = t >> 6;
    int col = lane * 4;
    float4 cs = *(const float4*)(colsum + col);
    float4 cq = *(const float4*)(colsq + col);
    float4 g4 = *(const float4*)(bng + col);
    float4 b4 = *(const float4*)(bnb + col);
    float4 scl, shf;
    float mu, var;
    mu = cs.x * invN; var = cq.x * invN - mu * mu; scl.x = g4.x * rsqrtf(var + EPSF); shf.x = b4.x - mu * scl.x;
    mu = cs.y * invN; var = cq.y * invN - mu * mu; scl.y = g4.y * rsqrtf(var + EPSF); shf.y = b4.y - mu * scl.y;
    mu = cs.z * invN; var = cq.z * invN - mu * mu; scl.z = g4.z * rsqrtf(var + EPSF); shf.z = b4.z - mu * scl.z;
    mu = cs.w * invN; var = cq.w * invN - mu * mu; scl.w = g4.w * rsqrtf(var + EPSF); shf.w = b4.w - mu * scl.w;
    int s = gstart[g], e = gstart[g + 1];
    float4 acc = make_float4(0.f, 0.f, 0.f, 0.f);
    for (int n = s + wv; n < e; n += 4) {
        float4 hv = bf4_to_f4(((const ushort4*)hb)[(size_t)n * 64 + lane]);
        float4 av = bf4_to_f4(((const ushort4*)aggb)[(size_t)n * 64 + lane]);
        acc.x += hv.x + fmaxf(av.x * scl.x + shf.x, 0.f);
        acc.y += hv.y + fmaxf(av.y * scl.y + shf.y, 0.f);
        acc.z += hv.z + fmaxf(av.z * scl.z + shf.z, 0.f);
        acc.w += hv.w + fmaxf(av.w * scl.w + shf.w, 0.f);
    }
    sm[wv][lane] = acc;
    __syncthreads();
    if (wv == 0) {
        float4 a = sm[0][lane], b = sm[1][lane], c = sm[2][lane], d = sm[3][lane];
        float inv = 1.0f / fmaxf((float)(e - s), 1.0f);
        prow[col + 0] = (a.x + b.x + c.x + d.x) * inv;
        prow[col + 1] = (a.y + b.y + c.y + d.y) * inv;
        prow[col + 2] = (a.z + b.z + c.z + d.z) * inv;
        prow[col + 3] = (a.w + b.w + c.w + d.w) * inv;
    }
    __syncthreads();
    // head
    if (t < 128) {
        float acc1 = b1[t];
        for (int k = 0; k < HH; ++k) acc1 += prow[k] * W1[(size_t)k * 128 + t];
        hred[t] = fmaxf(acc1, 0.f) * W2[t];
    }
    __syncthreads();
    for (int off = 64; off > 0; off >>= 1) {
        if (t < off) hred[t] += hred[t + off];
        __syncthreads();
    }
    if (t == 0) out[g] = hred[0] + b2[0];
}

extern "C" void kernel_launch(void* const* d_in, const int* in_sizes, int n_in,
                              void* d_out, int out_size, void* d_ws, size_t ws_size,
                              hipStream_t stream) {
    const int* x        = (const int*)d_in[0];
    const int* tags     = (const int*)d_in[1];
    const int* ei       = (const int*)d_in[2];
    const int* batch    = (const int*)d_in[3];
    const float* atom_e = (const float*)d_in[4];
    const float* tag_e  = (const float*)d_in[5];
    const float* Wp     = (const float*)d_in[6];
    const float* bp     = (const float*)d_in[7];
    const float* gcn_W  = (const float*)d_in[8];
    const float* gcn_b  = (const float*)d_in[9];
    const float* bn_g   = (const float*)d_in[10];
    const float* bn_b   = (const float*)d_in[11];
    const float* W1     = (const float*)d_in[12];
    const float* b1     = (const float*)d_in[13];
    const float* W2     = (const float*)d_in[14];
    const float* b2     = (const float*)d_in[15];
    float* out = (float*)d_out;

    const int N = NN, E = EE, G = GG, H = HH;
    const int Mpad = ((N + 127) / 128) * 128;  // 50048
    const float invN = 1.0f / (float)N;

    char* p = (char*)d_ws;
    auto alloc = [&](size_t bytes) {
        void* r = (void*)p;
        p += (bytes + 255) & ~(size_t)255;
        return r;
    };
    unsigned short* hbA = (unsigned short*)alloc((size_t)Mpad * H * 2);
    unsigned short* hbB = (unsigned short*)alloc((size_t)Mpad * H * 2);
    unsigned short* hwb = (unsigned short*)alloc((size_t)Mpad * H * 2);
    unsigned short* Wt  = (unsigned short*)alloc((size_t)LL * H * H * 2);
    unsigned short* aggb= (unsigned short*)alloc((size_t)N * H * 2);
    float* dinv = (float*)alloc((size_t)N * 4);
    int* rs     = (int*)alloc((size_t)N * 4);
    int* csr    = (int*)alloc((size_t)E * 4);
    int* bsum   = (int*)alloc(64 * 4);
    float* aref = (float*)alloc(100 * (size_t)H * 4);
    float* tref = (float*)alloc(3 * (size_t)H * 4);
    int* gstart = (int*)alloc((size_t)(G + 1) * 4);
    // zero-init region: cnt | cur | cstat[4][512] (contiguous allocs, one memset)
    int* cnt    = (int*)alloc((size_t)N * 4);
    int* cur    = (int*)alloc((size_t)N * 4);
    float* cstat= (float*)alloc((size_t)LL * 512 * 4);
    size_t zspan = (size_t)((char*)cstat + (size_t)LL * 512 * 4 - (char*)cnt);

    const int* src = ei;
    const int* dst = ei + E;

    hipMemsetAsync(cnt, 0, zspan, stream);

    k_degree<<<(E + 255) / 256, 256, 0, stream>>>(dst, cnt, E);
    int nb = (N + 1023) / 1024;
    k_scan1<<<nb, 1024, 0, stream>>>(cnt, rs, bsum, N);
    k_scan2<<<1, 64, 0, stream>>>(bsum, nb);
    k_scan3<<<(N + 255) / 256, 256, 0, stream>>>(rs, cnt, bsum, dinv, N);
    k_prep<<<3680, 256, 0, stream>>>(src, dst, rs, cur, csr, batch, gstart,
                                     atom_e, tag_e, Wp, bp, gcn_W, aref, tref, Wt);

    // ping-pong residual state: layer0 writes hbA; 1->hbB; 2->hbA; 3->hbB
    unsigned short* hbw[4] = {hbA, hbB, hbA, hbB};
    for (int l = 0; l < LL; ++l) {
        const unsigned short* hr = (l == 0) ? hbA : hbw[l - 1];
        const float* cprev = cstat + (size_t)(l > 0 ? l - 1 : 0) * 512;
        const float* bngp = bn_g + (size_t)(l > 0 ? l - 1 : 0) * H;
        const float* bnbp = bn_b + (size_t)(l > 0 ? l - 1 : 0) * H;
        k_gemm<<<dim3(Mpad / 128), 512, 0, stream>>>(
            hr, Wt + (size_t)l * H * H, dinv, hwb,
            (l == 0) ? 0 : 1, x, tags, aref, tref, aggb,
            cprev, cprev + 256, bngp, bnbp, hbw[l], N, invN);
        k_agg<<<(N + 3) / 4, 256, 0, stream>>>(hwb, aggb, csr, rs, cnt, dinv,
                                               gcn_b + (size_t)l * H, N);
        k_bnstats<<<512, 256, 0, stream>>>((const ushort4*)aggb,
                                           cstat + (size_t)l * 512,
                                           cstat + (size_t)l * 512 + 256, N);
    }

    k_poolhead<<<G, 256, 0, stream>>>(hbw[3], aggb, gstart,
                                      cstat + 3 * 512, cstat + 3 * 512 + 256,
                                      bn_g + 3 * (size_t)H, bn_b + 3 * (size_t)H,
                                      W1, b1, W2, b2, out, invN);
}